// Round 5
// baseline (280.304 us; speedup 1.0000x reference)
//
#include <hip/hip_runtime.h>
#include <hip/hip_cooperative_groups.h>
#include <math.h>

namespace cg = cooperative_groups;

// CapsuleLinear dynamic routing, fully fused into ONE cooperative kernel.
//   s[b,o,i]   = sum_n prob[b,o,n] * x[b,n,i]
//   out[b,o,l] = sum_i W[o,l,i] * s[b,o,i]
//   logits[b,o,n] = x[b,n,:] . T[b,o,:],  T accumulates t_r[o,i] = sum_l W[o,l,i]*v_r[o,l]
//
// R5: R4 post-mortem — all five kernels are individually fast (<40 us, below
// the harness-fill cutoff) but the 5-deep dependent chain pays ~10 us per
// kernel boundary (~50 us total). Fuse everything into one cooperative
// launch: T lives in LDS (never in global), 2 grid.sync()s replace 4 kernel
// boundaries. Pass body is byte-identical to R4's proven structure
// (broadcast VMEM x-loads, DPP+shfl softmax, pinned t[]).
// Fallback: if hipLaunchCooperativeKernel refuses, run the R4 5-kernel chain.

#define N_B      32
#define IN_CAPS  1152
#define IN_LEN   32
#define OUT_CAPS 64
#define OUT_LEN  32

#define NCHUNK 16                    // n-chunks per batch -> 32*16 = 512 blocks
#define NPB    (IN_CAPS / NCHUNK)    // 72 n per block
#define PASS_WAVES 4                 // 256-thread blocks
#define NPW    (NPB / PASS_WAVES)    // 18 n per wave
#define TSTR   36                    // padded LDS row stride (floats)

// DPP helper: butterfly step, all lanes valid.
#define DPPV(v, ctrl) \
    __int_as_float(__builtin_amdgcn_update_dpp(0, __float_as_int(v), ctrl, 0xF, 0xF, true))

__device__ __forceinline__ float wave_max(float v) {
    v = fmaxf(v, DPPV(v, 0xB1));         // quad_perm xor1
    v = fmaxf(v, DPPV(v, 0x4E));         // quad_perm xor2
    v = fmaxf(v, DPPV(v, 0x141));        // row_half_mirror (xor4 within 8)
    v = fmaxf(v, DPPV(v, 0x140));        // row_mirror (xor8 within 16)
    v = fmaxf(v, __shfl_xor(v, 16, 64)); // cross-row (proven path)
    v = fmaxf(v, __shfl_xor(v, 32, 64));
    return v;
}
__device__ __forceinline__ float wave_sum(float v) {
    v += DPPV(v, 0xB1);
    v += DPPV(v, 0x4E);
    v += DPPV(v, 0x141);
    v += DPPV(v, 0x140);
    v += __shfl_xor(v, 16, 64);
    v += __shfl_xor(v, 32, 64);
    return v;
}

// ---------------------------------------------------------------------------
// Fused cooperative kernel. Grid 512 = 32 batches x 16 chunks, 256 threads.
// LDS: T_lds (9 KB, persistent) + buf (36 KB, phase-aliased) = 46 KB
//   -> 2 blocks/CU co-resident (512 blocks on 256 CUs), validated by the
//      cooperative launch API.
// ---------------------------------------------------------------------------
__global__ __launch_bounds__(256, 2) void k_fused(const float* __restrict__ x,
                                                  const float* __restrict__ W,
                                                  float* __restrict__ part,
                                                  float* __restrict__ out) {
    const int b    = blockIdx.x >> 4;     // / NCHUNK
    const int c    = blockIdx.x & (NCHUNK - 1);
    const int tid  = threadIdx.x;
    const int lane = tid & 63;            // = output capsule o
    const int wave = __builtin_amdgcn_readfirstlane(tid >> 6);

    cg::grid_group grid = cg::this_grid();

    __shared__ __align__(16) float T_lds[OUT_CAPS * TSTR];               // 9 KB, persistent
    __shared__ __align__(16) float buf[PASS_WAVES * OUT_CAPS * TSTR];    // 36 KB, aliased

    // ======== phase 0: s0 = (1/64) sum_n x[b,n,:]  (redundant per block) ====
    {
        float4* red4 = (float4*)buf;                   // [32][8] float4 = 4 KB
        const int q = tid & 7, g = tid >> 3;
        const float* xb = x + (size_t)b * IN_CAPS * IN_LEN;
        float4 acc = make_float4(0.f, 0.f, 0.f, 0.f);
        for (int n = g; n < IN_CAPS; n += 32) {
            const float4 v = *(const float4*)(xb + n * IN_LEN + q * 4);
            acc.x += v.x; acc.y += v.y; acc.z += v.z; acc.w += v.w;
        }
        red4[g * 8 + q] = acc;
    }
    __syncthreads();
    float* u     = buf + 1024;   // 2048 floats
    float* scale = buf + 3072;   // 64
    float* s0    = buf + 3136;   // 32
    if (tid < 8) {
        const float4* red4 = (const float4*)buf;
        float4 v = make_float4(0.f, 0.f, 0.f, 0.f);
        for (int g = 0; g < 32; ++g) {
            const float4 r = red4[g * 8 + tid];
            v.x += r.x; v.y += r.y; v.z += r.z; v.w += r.w;
        }
        const float inv = 1.f / 64.f;       // uniform softmax prob at r=0
        s0[tid * 4 + 0] = v.x * inv;
        s0[tid * 4 + 1] = v.y * inv;
        s0[tid * 4 + 2] = v.z * inv;
        s0[tid * 4 + 3] = v.w * inv;
    }
    __syncthreads();

    // u = W @ s0
    for (int e = tid; e < OUT_CAPS * OUT_LEN; e += 256) {
        const float* wrow = W + (size_t)e * IN_LEN;
        float a = 0.f;
#pragma unroll
        for (int i = 0; i < IN_LEN; ++i) a = fmaf(wrow[i], s0[i], a);
        u[e] = a;
    }
    __syncthreads();
    if (tid < OUT_CAPS) {
        float ns = 0.f;
#pragma unroll
        for (int l = 0; l < OUT_LEN; ++l) { const float v = u[tid * OUT_LEN + l]; ns = fmaf(v, v, ns); }
        scale[tid] = sqrtf(ns) / (1.f + ns);
    }
    __syncthreads();
    // T_lds = W^T @ (u * scale)
    for (int e = tid; e < OUT_CAPS * IN_LEN; e += 256) {
        const int o = e >> 5, i = e & 31;
        float a = 0.f;
#pragma unroll
        for (int l = 0; l < OUT_LEN; ++l)
            a = fmaf(W[((size_t)o * OUT_LEN + l) * IN_LEN + i], u[o * OUT_LEN + l], a);
        T_lds[o * TSTR + i] = a * scale[o];
    }
    __syncthreads();

    // ======== pass phase (R4-proven body), used twice =======================
    auto do_pass = [&]() {
        float t[IN_LEN];
        {
#pragma unroll
            for (int q = 0; q < 8; ++q) {
                const float4 v = *(const float4*)&T_lds[lane * TSTR + q * 4];
                t[4 * q] = v.x; t[4 * q + 1] = v.y; t[4 * q + 2] = v.z; t[4 * q + 3] = v.w;
            }
        }
        asm volatile("" : "+v"(t[0]), "+v"(t[1]), "+v"(t[2]), "+v"(t[3]),
                          "+v"(t[4]), "+v"(t[5]), "+v"(t[6]), "+v"(t[7]),
                          "+v"(t[8]), "+v"(t[9]), "+v"(t[10]), "+v"(t[11]),
                          "+v"(t[12]), "+v"(t[13]), "+v"(t[14]), "+v"(t[15]));
        asm volatile("" : "+v"(t[16]), "+v"(t[17]), "+v"(t[18]), "+v"(t[19]),
                          "+v"(t[20]), "+v"(t[21]), "+v"(t[22]), "+v"(t[23]),
                          "+v"(t[24]), "+v"(t[25]), "+v"(t[26]), "+v"(t[27]),
                          "+v"(t[28]), "+v"(t[29]), "+v"(t[30]), "+v"(t[31]));

        float s[IN_LEN];
#pragma unroll
        for (int i = 0; i < IN_LEN; ++i) s[i] = 0.f;

        const float* xw = x + ((size_t)b * IN_CAPS + c * NPB + wave * NPW) * IN_LEN;

#define L4(acc, R, k) \
    acc = fmaf((R).x, t[k],     acc); acc = fmaf((R).y, t[k + 1], acc); \
    acc = fmaf((R).z, t[k + 2], acc); acc = fmaf((R).w, t[k + 3], acc);
#define S4(R, k) \
    s[k]     = fmaf(prob, (R).x, s[k]);     s[k + 1] = fmaf(prob, (R).y, s[k + 1]); \
    s[k + 2] = fmaf(prob, (R).z, s[k + 2]); s[k + 3] = fmaf(prob, (R).w, s[k + 3]);

#pragma unroll
        for (int j = 0; j < NPW; ++j) {
            const float4* xr = (const float4*)(xw + j * IN_LEN);  // wave-uniform addr
            const float4 r0 = xr[0], r1 = xr[1], r2 = xr[2], r3 = xr[3],
                         r4 = xr[4], r5 = xr[5], r6 = xr[6], r7 = xr[7];

            float l0 = 0.f, l1 = 0.f, l2 = 0.f, l3 = 0.f;
            L4(l0, r0, 0)  L4(l1, r1, 4)  L4(l2, r2, 8)  L4(l3, r3, 12)
            L4(l0, r4, 16) L4(l1, r5, 20) L4(l2, r6, 24) L4(l3, r7, 28)
            const float logit = (l0 + l1) + (l2 + l3);

            const float m = wave_max(logit);
            const float p = __expf(logit - m);
            const float S = wave_sum(p);
            const float prob = p * __builtin_amdgcn_rcpf(S);

            S4(r0, 0)  S4(r1, 4)  S4(r2, 8)  S4(r3, 12)
            S4(r4, 16) S4(r5, 20) S4(r6, 24) S4(r7, 28)
        }
#undef L4
#undef S4

        // flush: per-wave rows into padded buf, block-reduce, write part[b,c]
        {
            float4* dst = (float4*)&buf[(wave * OUT_CAPS + lane) * TSTR];
#pragma unroll
            for (int q = 0; q < 8; ++q)
                dst[q] = make_float4(s[4 * q], s[4 * q + 1], s[4 * q + 2], s[4 * q + 3]);
        }
        __syncthreads();
        {
            float4* pb4 = (float4*)(part + ((size_t)b * NCHUNK + c) * OUT_CAPS * IN_LEN);
            for (int e = tid; e < OUT_CAPS * IN_LEN / 4; e += 256) {
                const int o = e >> 3, q4 = (e & 7) * 4;
                const float4 a0 = *(const float4*)&buf[(0 * OUT_CAPS + o) * TSTR + q4];
                const float4 a1 = *(const float4*)&buf[(1 * OUT_CAPS + o) * TSTR + q4];
                const float4 a2 = *(const float4*)&buf[(2 * OUT_CAPS + o) * TSTR + q4];
                const float4 a3 = *(const float4*)&buf[(3 * OUT_CAPS + o) * TSTR + q4];
                pb4[e] = make_float4(a0.x + a1.x + a2.x + a3.x,
                                     a0.y + a1.y + a2.y + a3.y,
                                     a0.z + a1.z + a2.z + a3.z,
                                     a0.w + a1.w + a2.w + a3.w);
            }
        }
    };

    // ======== vt phase (redundant per block): s -> u -> squash ==============
    float* s_lds = buf;          // 2048 floats
    float* uu    = buf + 2048;   // 2048
    float* sc    = buf + 4096;   // 64
    auto do_vt_reduce = [&]() {
        const float4* pb4 = (const float4*)(part + (size_t)b * NCHUNK * OUT_CAPS * IN_LEN);
        for (int e = tid; e < OUT_CAPS * IN_LEN / 4; e += 256) {
            float4 acc = make_float4(0.f, 0.f, 0.f, 0.f);
#pragma unroll
            for (int cc = 0; cc < NCHUNK; ++cc) {
                const float4 v = pb4[cc * (OUT_CAPS * IN_LEN / 4) + e];
                acc.x += v.x; acc.y += v.y; acc.z += v.z; acc.w += v.w;
            }
            ((float4*)s_lds)[e] = acc;
        }
        __syncthreads();
        for (int e = tid; e < OUT_CAPS * OUT_LEN; e += 256) {
            const int o = e >> 5;
            const float* wrow = W + (size_t)e * IN_LEN;
            const float* srow = s_lds + o * IN_LEN;
            float a = 0.f;
#pragma unroll
            for (int i = 0; i < IN_LEN; ++i) a = fmaf(wrow[i], srow[i], a);
            uu[e] = a;
        }
        __syncthreads();
        if (tid < OUT_CAPS) {
            float ns = 0.f;
#pragma unroll
            for (int l = 0; l < OUT_LEN; ++l) { const float v = uu[tid * OUT_LEN + l]; ns = fmaf(v, v, ns); }
            sc[tid] = sqrtf(ns) / (1.f + ns);
        }
        __syncthreads();
    };

    // ======== routing iteration 1 ===========================================
    do_pass();
    grid.sync();
    do_vt_reduce();
    // T_lds += W^T @ (uu * sc)
    for (int e = tid; e < OUT_CAPS * IN_LEN; e += 256) {
        const int o = e >> 5, i = e & 31;
        float a = 0.f;
#pragma unroll
        for (int l = 0; l < OUT_LEN; ++l)
            a = fmaf(W[((size_t)o * OUT_LEN + l) * IN_LEN + i], uu[o * OUT_LEN + l], a);
        T_lds[o * TSTR + i] += a * sc[o];
    }
    __syncthreads();

    // ======== routing iteration 2 (final) ===================================
    do_pass();
    grid.sync();
    if (c != 0) return;                    // after last sync: only 1 block/batch finishes
    do_vt_reduce();
    for (int e = tid; e < OUT_CAPS * OUT_LEN; e += 256)
        out[(size_t)b * OUT_CAPS * OUT_LEN + e] = uu[e] * sc[e >> 5];
}

// ===========================================================================
// R4 fallback chain (proven): k_init -> k_pass -> k_vt -> k_pass -> k_vt
// ===========================================================================
__global__ __launch_bounds__(256) void k_init(const float* __restrict__ x,
                                              const float* __restrict__ W,
                                              float* __restrict__ T) {
    const int b   = blockIdx.x;
    const int tid = threadIdx.x;
    const float* xb = x + (size_t)b * IN_CAPS * IN_LEN;

    __shared__ float4 red4[32][8];
    {
        const int q = tid & 7;
        const int g = tid >> 3;
        float4 acc = make_float4(0.f, 0.f, 0.f, 0.f);
        for (int n = g; n < IN_CAPS; n += 32) {
            const float4 v = *(const float4*)(xb + n * IN_LEN + q * 4);
            acc.x += v.x; acc.y += v.y; acc.z += v.z; acc.w += v.w;
        }
        red4[g][q] = acc;
    }
    __syncthreads();
    __shared__ float s0[IN_LEN];
    if (tid < 8) {
        float4 v = make_float4(0.f, 0.f, 0.f, 0.f);
        for (int g = 0; g < 32; ++g) {
            const float4 r = red4[g][tid];
            v.x += r.x; v.y += r.y; v.z += r.z; v.w += r.w;
        }
        const float inv = 1.f / 64.f;
        s0[tid * 4 + 0] = v.x * inv;
        s0[tid * 4 + 1] = v.y * inv;
        s0[tid * 4 + 2] = v.z * inv;
        s0[tid * 4 + 3] = v.w * inv;
    }
    __syncthreads();

    __shared__ float u[OUT_CAPS * OUT_LEN];
    for (int e = tid; e < OUT_CAPS * OUT_LEN; e += 256) {
        const float* wrow = W + (size_t)e * IN_LEN;
        float a = 0.f;
#pragma unroll
        for (int i = 0; i < IN_LEN; ++i) a = fmaf(wrow[i], s0[i], a);
        u[e] = a;
    }
    __syncthreads();

    __shared__ float scale[OUT_CAPS];
    if (tid < OUT_CAPS) {
        float ns = 0.f;
#pragma unroll
        for (int l = 0; l < OUT_LEN; ++l) { const float v = u[tid * OUT_LEN + l]; ns = fmaf(v, v, ns); }
        scale[tid] = sqrtf(ns) / (1.f + ns);
    }
    __syncthreads();

    for (int e = tid; e < OUT_CAPS * IN_LEN; e += 256) {
        const int o = e >> 5, i = e & 31;
        float a = 0.f;
#pragma unroll
        for (int l = 0; l < OUT_LEN; ++l)
            a = fmaf(W[((size_t)o * OUT_LEN + l) * IN_LEN + i], u[o * OUT_LEN + l], a);
        T[(size_t)b * OUT_CAPS * IN_LEN + e] = a * scale[o];
    }
}

__global__ __launch_bounds__(256, 2) void k_pass(const float* __restrict__ x,
                                                 const float* __restrict__ T,
                                                 float* __restrict__ part) {
    const int b    = blockIdx.x >> 4;
    const int c    = blockIdx.x & (NCHUNK - 1);
    const int tid  = threadIdx.x;
    const int lane = tid & 63;
    const int wave = __builtin_amdgcn_readfirstlane(tid >> 6);

    float t[IN_LEN];
    {
        const float4* Trow4 = (const float4*)(T + ((size_t)b * OUT_CAPS + lane) * IN_LEN);
#pragma unroll
        for (int q = 0; q < 8; ++q) {
            const float4 v = Trow4[q];
            t[4 * q] = v.x; t[4 * q + 1] = v.y; t[4 * q + 2] = v.z; t[4 * q + 3] = v.w;
        }
    }
    asm volatile("" : "+v"(t[0]), "+v"(t[1]), "+v"(t[2]), "+v"(t[3]),
                      "+v"(t[4]), "+v"(t[5]), "+v"(t[6]), "+v"(t[7]),
                      "+v"(t[8]), "+v"(t[9]), "+v"(t[10]), "+v"(t[11]),
                      "+v"(t[12]), "+v"(t[13]), "+v"(t[14]), "+v"(t[15]));
    asm volatile("" : "+v"(t[16]), "+v"(t[17]), "+v"(t[18]), "+v"(t[19]),
                      "+v"(t[20]), "+v"(t[21]), "+v"(t[22]), "+v"(t[23]),
                      "+v"(t[24]), "+v"(t[25]), "+v"(t[26]), "+v"(t[27]),
                      "+v"(t[28]), "+v"(t[29]), "+v"(t[30]), "+v"(t[31]));

    float s[IN_LEN];
#pragma unroll
    for (int i = 0; i < IN_LEN; ++i) s[i] = 0.f;

    const float* xw = x + ((size_t)b * IN_CAPS + c * NPB + wave * NPW) * IN_LEN;

#define L4(acc, R, k) \
    acc = fmaf((R).x, t[k],     acc); acc = fmaf((R).y, t[k + 1], acc); \
    acc = fmaf((R).z, t[k + 2], acc); acc = fmaf((R).w, t[k + 3], acc);
#define S4(R, k) \
    s[k]     = fmaf(prob, (R).x, s[k]);     s[k + 1] = fmaf(prob, (R).y, s[k + 1]); \
    s[k + 2] = fmaf(prob, (R).z, s[k + 2]); s[k + 3] = fmaf(prob, (R).w, s[k + 3]);

#pragma unroll
    for (int j = 0; j < NPW; ++j) {
        const float4* xr = (const float4*)(xw + j * IN_LEN);
        const float4 r0 = xr[0], r1 = xr[1], r2 = xr[2], r3 = xr[3],
                     r4 = xr[4], r5 = xr[5], r6 = xr[6], r7 = xr[7];

        float l0 = 0.f, l1 = 0.f, l2 = 0.f, l3 = 0.f;
        L4(l0, r0, 0)  L4(l1, r1, 4)  L4(l2, r2, 8)  L4(l3, r3, 12)
        L4(l0, r4, 16) L4(l1, r5, 20) L4(l2, r6, 24) L4(l3, r7, 28)
        const float logit = (l0 + l1) + (l2 + l3);

        const float m = wave_max(logit);
        const float p = __expf(logit - m);
        const float S = wave_sum(p);
        const float prob = p * __builtin_amdgcn_rcpf(S);

        S4(r0, 0)  S4(r1, 4)  S4(r2, 8)  S4(r3, 12)
        S4(r4, 16) S4(r5, 20) S4(r6, 24) S4(r7, 28)
    }
#undef L4
#undef S4

    __shared__ __align__(16) float sp[PASS_WAVES][OUT_CAPS][TSTR];
    {
        float4* dst = (float4*)&sp[wave][lane][0];
#pragma unroll
        for (int q = 0; q < 8; ++q)
            dst[q] = make_float4(s[4 * q], s[4 * q + 1], s[4 * q + 2], s[4 * q + 3]);
    }
    __syncthreads();
    {
        float4* pb4 = (float4*)(part + ((size_t)b * NCHUNK + c) * OUT_CAPS * IN_LEN);
        for (int e = tid; e < OUT_CAPS * IN_LEN / 4; e += 256) {
            const int o = e >> 3, q4 = (e & 7) * 4;
            const float4 a0 = *(const float4*)&sp[0][o][q4];
            const float4 a1 = *(const float4*)&sp[1][o][q4];
            const float4 a2 = *(const float4*)&sp[2][o][q4];
            const float4 a3 = *(const float4*)&sp[3][o][q4];
            pb4[e] = make_float4(a0.x + a1.x + a2.x + a3.x,
                                 a0.y + a1.y + a2.y + a3.y,
                                 a0.z + a1.z + a2.z + a3.z,
                                 a0.w + a1.w + a2.w + a3.w);
        }
    }
}

__global__ __launch_bounds__(256) void k_vt(const float* __restrict__ W,
                                            const float* __restrict__ part,
                                            float* __restrict__ T,
                                            float* __restrict__ out,
                                            int final_iter) {
    const int b   = blockIdx.x;
    const int tid = threadIdx.x;

    __shared__ float s_lds[OUT_CAPS * IN_LEN];
    {
        const float4* pb4 = (const float4*)(part + (size_t)b * NCHUNK * OUT_CAPS * IN_LEN);
        for (int e = tid; e < OUT_CAPS * IN_LEN / 4; e += 256) {
            float4 acc = make_float4(0.f, 0.f, 0.f, 0.f);
#pragma unroll
            for (int c = 0; c < NCHUNK; ++c) {
                const float4 v = pb4[c * (OUT_CAPS * IN_LEN / 4) + e];
                acc.x += v.x; acc.y += v.y; acc.z += v.z; acc.w += v.w;
            }
            ((float4*)s_lds)[e] = acc;
        }
    }
    __syncthreads();

    __shared__ float u[OUT_CAPS * OUT_LEN];
    for (int e = tid; e < OUT_CAPS * OUT_LEN; e += 256) {
        const int o = e >> 5;
        const float* wrow = W + (size_t)e * IN_LEN;
        const float* srow = s_lds + o * IN_LEN;
        float a = 0.f;
#pragma unroll
        for (int i = 0; i < IN_LEN; ++i) a = fmaf(wrow[i], srow[i], a);
        u[e] = a;
    }
    __syncthreads();

    __shared__ float scale[OUT_CAPS];
    if (tid < OUT_CAPS) {
        float ns = 0.f;
#pragma unroll
        for (int l = 0; l < OUT_LEN; ++l) { const float v = u[tid * OUT_LEN + l]; ns = fmaf(v, v, ns); }
        scale[tid] = sqrtf(ns) / (1.f + ns);
    }
    __syncthreads();

    if (final_iter) {
        for (int e = tid; e < OUT_CAPS * OUT_LEN; e += 256)
            out[(size_t)b * OUT_CAPS * OUT_LEN + e] = u[e] * scale[e >> 5];
    } else {
        for (int e = tid; e < OUT_CAPS * IN_LEN; e += 256) {
            const int o = e >> 5, i = e & 31;
            float a = 0.f;
#pragma unroll
            for (int l = 0; l < OUT_LEN; ++l)
                a = fmaf(W[((size_t)o * OUT_LEN + l) * IN_LEN + i], u[o * OUT_LEN + l], a);
            T[(size_t)b * OUT_CAPS * IN_LEN + e] += a * scale[o];
        }
    }
}

extern "C" void kernel_launch(void* const* d_in, const int* in_sizes, int n_in,
                              void* d_out, int out_size, void* d_ws, size_t ws_size,
                              hipStream_t stream) {
    const float* x = (const float*)d_in[0];   // [32,1152,32]
    const float* W = (const float*)d_in[1];   // [64,32,32]
    float* out = (float*)d_out;               // [32,64,32]

    float* T    = (float*)d_ws;                         // 32*64*32 floats (256 KB)
    float* part = T + (size_t)N_B * OUT_CAPS * IN_LEN;  // 32*16*64*32 floats (4 MB)

    void* args[] = { (void*)&x, (void*)&W, (void*)&part, (void*)&out };
    hipError_t err = hipLaunchCooperativeKernel((const void*)k_fused,
                                                dim3(N_B * NCHUNK), dim3(256),
                                                args, 0, stream);
    if (err != hipSuccess) {
        // fallback: R4-proven 5-kernel chain
        k_init<<<N_B, 256, 0, stream>>>(x, W, T);
        k_pass<<<N_B * NCHUNK, 256, 0, stream>>>(x, T, part);
        k_vt  <<<N_B, 256, 0, stream>>>(W, part, T, out, 0);
        k_pass<<<N_B * NCHUNK, 256, 0, stream>>>(x, T, part);
        k_vt  <<<N_B, 256, 0, stream>>>(W, part, T, out, 1);
    }
}

// Round 6
// 142.260 us; speedup vs baseline: 1.9704x; 1.9704x over previous
//
#include <hip/hip_runtime.h>
#include <math.h>

// CapsuleLinear dynamic routing, `priors` never materialized.
//   s[b,o,i]   = sum_n prob[b,o,n] * x[b,n,i]
//   out[b,o,l] = sum_i W[o,l,i] * s[b,o,i]
//   logits[b,o,n] = x[b,n,:] . T[b,o,:],  T accumulates t_r[o,i] = sum_l W[o,l,i]*v_r[o,l]
//
// R6: 3-kernel chain. R5 post-mortem: grid.sync()/threadfence on non-coherent
// XCD L2s forces L2 invalidation -> 44 MB HBM re-reads (207 us). Kernel
// boundaries are the cheap ordering primitive here. So: cut the R4 5-chain to
// 3 by REDUNDANT per-block compute (no cross-block sync):
//   kA: redundant init (R5-proven phase 0) -> T0 in LDS (+global for kB), pass1
//   kB: redundant vt-reduce (R5-proven) -> T1 in LDS, pass2
//   kC: final vt split by o-group: 256 blocks x 16 KB reads, latency-friendly
// Pass body byte-identical to R4's proven structure (broadcast VMEM x loads,
// DPP+shfl softmax, pinned t[]).

#define N_B      32
#define IN_CAPS  1152
#define IN_LEN   32
#define OUT_CAPS 64
#define OUT_LEN  32

#define NCHUNK 16                    // n-chunks per batch -> 32*16 = 512 blocks
#define NPB    (IN_CAPS / NCHUNK)    // 72 n per block
#define PASS_WAVES 4                 // 256-thread blocks
#define NPW    (NPB / PASS_WAVES)    // 18 n per wave
#define TSTR   36                    // padded LDS row stride (floats)

// DPP helper: butterfly step, all lanes valid.
#define DPPV(v, ctrl) \
    __int_as_float(__builtin_amdgcn_update_dpp(0, __float_as_int(v), ctrl, 0xF, 0xF, true))

__device__ __forceinline__ float wave_max(float v) {
    v = fmaxf(v, DPPV(v, 0xB1));         // quad_perm xor1
    v = fmaxf(v, DPPV(v, 0x4E));         // quad_perm xor2
    v = fmaxf(v, DPPV(v, 0x141));        // row_half_mirror (xor4 within 8)
    v = fmaxf(v, DPPV(v, 0x140));        // row_mirror (xor8 within 16)
    v = fmaxf(v, __shfl_xor(v, 16, 64)); // cross-row (proven path)
    v = fmaxf(v, __shfl_xor(v, 32, 64));
    return v;
}
__device__ __forceinline__ float wave_sum(float v) {
    v += DPPV(v, 0xB1);
    v += DPPV(v, 0x4E);
    v += DPPV(v, 0x141);
    v += DPPV(v, 0x140);
    v += __shfl_xor(v, 16, 64);
    v += __shfl_xor(v, 32, 64);
    return v;
}

// ---------------------------------------------------------------------------
// R4-proven pass body: logits from pinned t[] vs broadcast x rows, DPP+shfl
// softmax over 64 lanes (= o), s accumulate, padded-LDS flush -> part[b,c].
// ---------------------------------------------------------------------------
__device__ __forceinline__ void pass_and_flush(const float* __restrict__ x,
                                               const float* T_lds, float* buf,
                                               float* __restrict__ part,
                                               int b, int c, int tid, int lane, int wave) {
    float t[IN_LEN];
    {
#pragma unroll
        for (int q = 0; q < 8; ++q) {
            const float4 v = *(const float4*)&T_lds[lane * TSTR + q * 4];
            t[4 * q] = v.x; t[4 * q + 1] = v.y; t[4 * q + 2] = v.z; t[4 * q + 3] = v.w;
        }
    }
    asm volatile("" : "+v"(t[0]), "+v"(t[1]), "+v"(t[2]), "+v"(t[3]),
                      "+v"(t[4]), "+v"(t[5]), "+v"(t[6]), "+v"(t[7]),
                      "+v"(t[8]), "+v"(t[9]), "+v"(t[10]), "+v"(t[11]),
                      "+v"(t[12]), "+v"(t[13]), "+v"(t[14]), "+v"(t[15]));
    asm volatile("" : "+v"(t[16]), "+v"(t[17]), "+v"(t[18]), "+v"(t[19]),
                      "+v"(t[20]), "+v"(t[21]), "+v"(t[22]), "+v"(t[23]),
                      "+v"(t[24]), "+v"(t[25]), "+v"(t[26]), "+v"(t[27]),
                      "+v"(t[28]), "+v"(t[29]), "+v"(t[30]), "+v"(t[31]));

    float s[IN_LEN];
#pragma unroll
    for (int i = 0; i < IN_LEN; ++i) s[i] = 0.f;

    const float* xw = x + ((size_t)b * IN_CAPS + c * NPB + wave * NPW) * IN_LEN;

#define L4(acc, R, k) \
    acc = fmaf((R).x, t[k],     acc); acc = fmaf((R).y, t[k + 1], acc); \
    acc = fmaf((R).z, t[k + 2], acc); acc = fmaf((R).w, t[k + 3], acc);
#define S4(R, k) \
    s[k]     = fmaf(prob, (R).x, s[k]);     s[k + 1] = fmaf(prob, (R).y, s[k + 1]); \
    s[k + 2] = fmaf(prob, (R).z, s[k + 2]); s[k + 3] = fmaf(prob, (R).w, s[k + 3]);

#pragma unroll
    for (int j = 0; j < NPW; ++j) {
        const float4* xr = (const float4*)(xw + j * IN_LEN);  // wave-uniform addr
        const float4 r0 = xr[0], r1 = xr[1], r2 = xr[2], r3 = xr[3],
                     r4 = xr[4], r5 = xr[5], r6 = xr[6], r7 = xr[7];

        float l0 = 0.f, l1 = 0.f, l2 = 0.f, l3 = 0.f;
        L4(l0, r0, 0)  L4(l1, r1, 4)  L4(l2, r2, 8)  L4(l3, r3, 12)
        L4(l0, r4, 16) L4(l1, r5, 20) L4(l2, r6, 24) L4(l3, r7, 28)
        const float logit = (l0 + l1) + (l2 + l3);

        const float m = wave_max(logit);
        const float p = __expf(logit - m);
        const float S = wave_sum(p);
        const float prob = p * __builtin_amdgcn_rcpf(S);

        S4(r0, 0)  S4(r1, 4)  S4(r2, 8)  S4(r3, 12)
        S4(r4, 16) S4(r5, 20) S4(r6, 24) S4(r7, 28)
    }
#undef L4
#undef S4

    // flush: per-wave rows into padded buf, block-reduce, write part[b,c]
    {
        float4* dst = (float4*)&buf[(wave * OUT_CAPS + lane) * TSTR];
#pragma unroll
        for (int q = 0; q < 8; ++q)
            dst[q] = make_float4(s[4 * q], s[4 * q + 1], s[4 * q + 2], s[4 * q + 3]);
    }
    __syncthreads();
    {
        float4* pb4 = (float4*)(part + ((size_t)b * NCHUNK + c) * OUT_CAPS * IN_LEN);
        for (int e = tid; e < OUT_CAPS * IN_LEN / 4; e += 256) {
            const int o = e >> 3, q4 = (e & 7) * 4;
            const float4 a0 = *(const float4*)&buf[(0 * OUT_CAPS + o) * TSTR + q4];
            const float4 a1 = *(const float4*)&buf[(1 * OUT_CAPS + o) * TSTR + q4];
            const float4 a2 = *(const float4*)&buf[(2 * OUT_CAPS + o) * TSTR + q4];
            const float4 a3 = *(const float4*)&buf[(3 * OUT_CAPS + o) * TSTR + q4];
            pb4[e] = make_float4(a0.x + a1.x + a2.x + a3.x,
                                 a0.y + a1.y + a2.y + a3.y,
                                 a0.z + a1.z + a2.z + a3.z,
                                 a0.w + a1.w + a2.w + a3.w);
        }
    }
}

// ---------------------------------------------------------------------------
// kA: redundant init per block (T0 -> LDS; c==0 also -> global T), then pass1.
// ---------------------------------------------------------------------------
__global__ __launch_bounds__(256, 2) void kA(const float* __restrict__ x,
                                             const float* __restrict__ W,
                                             float* __restrict__ T,
                                             float* __restrict__ part) {
    const int b    = blockIdx.x >> 4;     // / NCHUNK
    const int c    = blockIdx.x & (NCHUNK - 1);
    const int tid  = threadIdx.x;
    const int lane = tid & 63;            // = output capsule o
    const int wave = __builtin_amdgcn_readfirstlane(tid >> 6);

    __shared__ __align__(16) float T_lds[OUT_CAPS * TSTR];               // 9 KB
    __shared__ __align__(16) float buf[PASS_WAVES * OUT_CAPS * TSTR];    // 36 KB

    // ---- redundant init (R5-proven phase 0) ----
    {
        float4* red4 = (float4*)buf;                   // [32][8] float4
        const int q = tid & 7, g = tid >> 3;
        const float* xb = x + (size_t)b * IN_CAPS * IN_LEN;
        float4 acc = make_float4(0.f, 0.f, 0.f, 0.f);
        for (int n = g; n < IN_CAPS; n += 32) {
            const float4 v = *(const float4*)(xb + n * IN_LEN + q * 4);
            acc.x += v.x; acc.y += v.y; acc.z += v.z; acc.w += v.w;
        }
        red4[g * 8 + q] = acc;
    }
    __syncthreads();
    float* u     = buf + 1024;   // 2048 floats
    float* scale = buf + 3072;   // 64
    float* s0    = buf + 3136;   // 32
    if (tid < 8) {
        const float4* red4 = (const float4*)buf;
        float4 v = make_float4(0.f, 0.f, 0.f, 0.f);
        for (int g = 0; g < 32; ++g) {
            const float4 r = red4[g * 8 + tid];
            v.x += r.x; v.y += r.y; v.z += r.z; v.w += r.w;
        }
        const float inv = 1.f / 64.f;       // uniform softmax prob at r=0
        s0[tid * 4 + 0] = v.x * inv;
        s0[tid * 4 + 1] = v.y * inv;
        s0[tid * 4 + 2] = v.z * inv;
        s0[tid * 4 + 3] = v.w * inv;
    }
    __syncthreads();

    for (int e = tid; e < OUT_CAPS * OUT_LEN; e += 256) {
        const float* wrow = W + (size_t)e * IN_LEN;
        float a = 0.f;
#pragma unroll
        for (int i = 0; i < IN_LEN; ++i) a = fmaf(wrow[i], s0[i], a);
        u[e] = a;
    }
    __syncthreads();
    if (tid < OUT_CAPS) {
        float ns = 0.f;
#pragma unroll
        for (int l = 0; l < OUT_LEN; ++l) { const float v = u[tid * OUT_LEN + l]; ns = fmaf(v, v, ns); }
        scale[tid] = sqrtf(ns) / (1.f + ns);
    }
    __syncthreads();
    for (int e = tid; e < OUT_CAPS * IN_LEN; e += 256) {
        const int o = e >> 5, i = e & 31;
        float a = 0.f;
#pragma unroll
        for (int l = 0; l < OUT_LEN; ++l)
            a = fmaf(W[((size_t)o * OUT_LEN + l) * IN_LEN + i], u[o * OUT_LEN + l], a);
        T_lds[o * TSTR + i] = a * scale[o];
    }
    __syncthreads();

    // c==0 block publishes T0 for kB (normal kernel-boundary visibility)
    if (c == 0) {
        for (int e = tid; e < OUT_CAPS * IN_LEN; e += 256)
            T[(size_t)b * OUT_CAPS * IN_LEN + e] = T_lds[(e >> 5) * TSTR + (e & 31)];
    }

    pass_and_flush(x, T_lds, buf, part, b, c, tid, lane, wave);
}

// ---------------------------------------------------------------------------
// kB: redundant vt-reduce per block (s -> u -> squash; T1 = T0 + W^T v1 into
//     LDS), then pass2. part from kA is L3-resident across the boundary.
// ---------------------------------------------------------------------------
__global__ __launch_bounds__(256, 2) void kB(const float* __restrict__ x,
                                             const float* __restrict__ W,
                                             const float* __restrict__ T,
                                             float* __restrict__ part) {
    const int b    = blockIdx.x >> 4;
    const int c    = blockIdx.x & (NCHUNK - 1);
    const int tid  = threadIdx.x;
    const int lane = tid & 63;
    const int wave = __builtin_amdgcn_readfirstlane(tid >> 6);

    __shared__ __align__(16) float T_lds[OUT_CAPS * TSTR];
    __shared__ __align__(16) float buf[PASS_WAVES * OUT_CAPS * TSTR];

    float* s_lds = buf;          // 2048 floats
    float* uu    = buf + 2048;   // 2048
    float* sc    = buf + 4096;   // 64

    // ---- redundant vt-reduce (R5-proven) ----
    {
        const float4* pb4 = (const float4*)(part + (size_t)b * NCHUNK * OUT_CAPS * IN_LEN);
        for (int e = tid; e < OUT_CAPS * IN_LEN / 4; e += 256) {
            float4 acc = make_float4(0.f, 0.f, 0.f, 0.f);
#pragma unroll
            for (int cc = 0; cc < NCHUNK; ++cc) {
                const float4 v = pb4[cc * (OUT_CAPS * IN_LEN / 4) + e];
                acc.x += v.x; acc.y += v.y; acc.z += v.z; acc.w += v.w;
            }
            ((float4*)s_lds)[e] = acc;
        }
    }
    __syncthreads();
    for (int e = tid; e < OUT_CAPS * OUT_LEN; e += 256) {
        const int o = e >> 5;
        const float* wrow = W + (size_t)e * IN_LEN;
        const float* srow = s_lds + o * IN_LEN;
        float a = 0.f;
#pragma unroll
        for (int i = 0; i < IN_LEN; ++i) a = fmaf(wrow[i], srow[i], a);
        uu[e] = a;
    }
    __syncthreads();
    if (tid < OUT_CAPS) {
        float ns = 0.f;
#pragma unroll
        for (int l = 0; l < OUT_LEN; ++l) { const float v = uu[tid * OUT_LEN + l]; ns = fmaf(v, v, ns); }
        sc[tid] = sqrtf(ns) / (1.f + ns);
    }
    __syncthreads();

    // T1 = T0 + W^T @ (uu * sc)  -> LDS
    for (int e = tid; e < OUT_CAPS * IN_LEN; e += 256) {
        const int o = e >> 5, i = e & 31;
        float a = 0.f;
#pragma unroll
        for (int l = 0; l < OUT_LEN; ++l)
            a = fmaf(W[((size_t)o * OUT_LEN + l) * IN_LEN + i], uu[o * OUT_LEN + l], a);
        T_lds[o * TSTR + i] = T[(size_t)b * OUT_CAPS * IN_LEN + e] + a * sc[o];
    }
    __syncthreads();

    pass_and_flush(x, T_lds, buf, part, b, c, tid, lane, wave);
}

// ---------------------------------------------------------------------------
// kC: final vt, split by o-group. 256 blocks = 32 b x 8 groups of 8 o.
//     thread (ol, i): s[o,i] = sum_c part; then (ol, l): u -> squash -> out.
// ---------------------------------------------------------------------------
__global__ __launch_bounds__(256) void kC(const float* __restrict__ W,
                                          const float* __restrict__ part,
                                          float* __restrict__ out) {
    const int b   = blockIdx.x >> 3;
    const int og  = blockIdx.x & 7;
    const int tid = threadIdx.x;
    const int ol  = tid >> 5;            // 0..7 local o
    const int i   = tid & 31;            // input index / later l
    const int o   = og * 8 + ol;

    // s[o,i] = sum_c part[b,c,o,i]  (coalesced: 8 rows x 128 B per c)
    float a = 0.f;
    const float* pb = part + (size_t)b * NCHUNK * OUT_CAPS * IN_LEN + o * IN_LEN + i;
#pragma unroll
    for (int cc = 0; cc < NCHUNK; ++cc) a += pb[cc * OUT_CAPS * IN_LEN];

    __shared__ float s_lds[8][33];
    s_lds[ol][i] = a;
    __syncthreads();

    // u[o,l] with l = i; W rows L2-resident
    const float* wrow = W + ((size_t)o * OUT_LEN + i) * IN_LEN;
    float u = 0.f;
#pragma unroll
    for (int k = 0; k < IN_LEN; ++k) u = fmaf(wrow[k], s_lds[ol][k], u);

    // ns = sum_l u^2 over the 32 lanes of this o (offsets <32 stay in-half)
    float ns = u * u;
    ns += __shfl_xor(ns, 1, 64);
    ns += __shfl_xor(ns, 2, 64);
    ns += __shfl_xor(ns, 4, 64);
    ns += __shfl_xor(ns, 8, 64);
    ns += __shfl_xor(ns, 16, 64);
    const float scale = sqrtf(ns) / (1.f + ns);

    out[((size_t)b * OUT_CAPS + o) * OUT_LEN + i] = u * scale;
}

extern "C" void kernel_launch(void* const* d_in, const int* in_sizes, int n_in,
                              void* d_out, int out_size, void* d_ws, size_t ws_size,
                              hipStream_t stream) {
    const float* x = (const float*)d_in[0];   // [32,1152,32]
    const float* W = (const float*)d_in[1];   // [64,32,32]
    float* out = (float*)d_out;               // [32,64,32]

    float* T    = (float*)d_ws;                         // 32*64*32 floats (256 KB)
    float* part = T + (size_t)N_B * OUT_CAPS * IN_LEN;  // 32*16*64*32 floats (4 MB)

    kA<<<N_B * NCHUNK, 256, 0, stream>>>(x, W, T, part);   // init + routing iter 1
    kB<<<N_B * NCHUNK, 256, 0, stream>>>(x, W, T, part);   // vt1 + routing iter 2
    kC<<<N_B * 8,      256, 0, stream>>>(W, part, out);    // final vt, o-split
}

// Round 7
// 130.002 us; speedup vs baseline: 2.1562x; 1.0943x over previous
//
#include <hip/hip_runtime.h>
#include <math.h>

// CapsuleLinear dynamic routing, `priors` never materialized.
//   s[b,o,i]   = sum_n prob[b,o,n] * x[b,n,i]
//   out[b,o,l] = sum_i W[o,l,i] * s[b,o,i]
//   logits[b,o,n] = x[b,n,:] . T[b,o,:],  T accumulates t_r[o,i] = sum_l W[o,l,i]*v_r[o,l]
//
// R7: 4-kernel chain  k_init -> pass1 -> kB(vt1+pass2) -> kC(final vt).
// R6 post-mortem: redundant T0-init in kA re-read L3-cold x 4.3x from HBM
// (FETCH 20.5 MB, 50 us) -> revert to R4's k_init(32 blocks warms x once) +
// k_pass split. Keep R6's kB merge (redundant vt-reduce of L2/L3-warm part)
// and parallel kC. Fix R6's latent part read/write race: iter-2 partials go
// to a separate part2 buffer. Add XCD-aware (b,c) swizzle (bijective,
// 512%8==0) so a batch's 16 chunks share one XCD's L2 (x slab + part slabs
// fetched once per L2 instead of ~8x).

#define N_B      32
#define IN_CAPS  1152
#define IN_LEN   32
#define OUT_CAPS 64
#define OUT_LEN  32

#define NCHUNK 16                    // n-chunks per batch -> 32*16 = 512 blocks
#define NPB    (IN_CAPS / NCHUNK)    // 72 n per block
#define PASS_WAVES 4                 // 256-thread blocks
#define NPW    (NPB / PASS_WAVES)    // 18 n per wave
#define TSTR   36                    // padded LDS row stride (floats)

// XCD-aware decode of blockIdx.x -> (b,c): presumed round-robin XCD = d&7;
// gives each XCD 4 whole batches. Pure perf heuristic, bijective.
#define DECODE_BC(d, b, c) \
    const int _slot = (d) >> 3; \
    const int b = ((d) & 7) * 4 + (_slot >> 4); \
    const int c = _slot & 15;

// DPP helper: butterfly step, all lanes valid.
#define DPPV(v, ctrl) \
    __int_as_float(__builtin_amdgcn_update_dpp(0, __float_as_int(v), ctrl, 0xF, 0xF, true))

__device__ __forceinline__ float wave_max(float v) {
    v = fmaxf(v, DPPV(v, 0xB1));         // quad_perm xor1
    v = fmaxf(v, DPPV(v, 0x4E));         // quad_perm xor2
    v = fmaxf(v, DPPV(v, 0x141));        // row_half_mirror (xor4 within 8)
    v = fmaxf(v, DPPV(v, 0x140));        // row_mirror (xor8 within 16)
    v = fmaxf(v, __shfl_xor(v, 16, 64)); // cross-row (proven path)
    v = fmaxf(v, __shfl_xor(v, 32, 64));
    return v;
}
__device__ __forceinline__ float wave_sum(float v) {
    v += DPPV(v, 0xB1);
    v += DPPV(v, 0x4E);
    v += DPPV(v, 0x141);
    v += DPPV(v, 0x140);
    v += __shfl_xor(v, 16, 64);
    v += __shfl_xor(v, 32, 64);
    return v;
}

// ---------------------------------------------------------------------------
// R4-proven pass body: logits from pinned t[] vs broadcast x rows, DPP+shfl
// softmax over 64 lanes (= o), s accumulate, padded-LDS flush -> part[b,c].
// ---------------------------------------------------------------------------
__device__ __forceinline__ void pass_and_flush(const float* __restrict__ x,
                                               const float* T_row_src, int t_stride,
                                               float* buf,
                                               float* __restrict__ part_out,
                                               int b, int c, int tid, int lane, int wave) {
    float t[IN_LEN];
    {
#pragma unroll
        for (int q = 0; q < 8; ++q) {
            const float4 v = *(const float4*)&T_row_src[lane * t_stride + q * 4];
            t[4 * q] = v.x; t[4 * q + 1] = v.y; t[4 * q + 2] = v.z; t[4 * q + 3] = v.w;
        }
    }
    asm volatile("" : "+v"(t[0]), "+v"(t[1]), "+v"(t[2]), "+v"(t[3]),
                      "+v"(t[4]), "+v"(t[5]), "+v"(t[6]), "+v"(t[7]),
                      "+v"(t[8]), "+v"(t[9]), "+v"(t[10]), "+v"(t[11]),
                      "+v"(t[12]), "+v"(t[13]), "+v"(t[14]), "+v"(t[15]));
    asm volatile("" : "+v"(t[16]), "+v"(t[17]), "+v"(t[18]), "+v"(t[19]),
                      "+v"(t[20]), "+v"(t[21]), "+v"(t[22]), "+v"(t[23]),
                      "+v"(t[24]), "+v"(t[25]), "+v"(t[26]), "+v"(t[27]),
                      "+v"(t[28]), "+v"(t[29]), "+v"(t[30]), "+v"(t[31]));

    float s[IN_LEN];
#pragma unroll
    for (int i = 0; i < IN_LEN; ++i) s[i] = 0.f;

    const float* xw = x + ((size_t)b * IN_CAPS + c * NPB + wave * NPW) * IN_LEN;

#define L4(acc, R, k) \
    acc = fmaf((R).x, t[k],     acc); acc = fmaf((R).y, t[k + 1], acc); \
    acc = fmaf((R).z, t[k + 2], acc); acc = fmaf((R).w, t[k + 3], acc);
#define S4(R, k) \
    s[k]     = fmaf(prob, (R).x, s[k]);     s[k + 1] = fmaf(prob, (R).y, s[k + 1]); \
    s[k + 2] = fmaf(prob, (R).z, s[k + 2]); s[k + 3] = fmaf(prob, (R).w, s[k + 3]);

#pragma unroll
    for (int j = 0; j < NPW; ++j) {
        const float4* xr = (const float4*)(xw + j * IN_LEN);  // wave-uniform addr
        const float4 r0 = xr[0], r1 = xr[1], r2 = xr[2], r3 = xr[3],
                     r4 = xr[4], r5 = xr[5], r6 = xr[6], r7 = xr[7];

        float l0 = 0.f, l1 = 0.f, l2 = 0.f, l3 = 0.f;
        L4(l0, r0, 0)  L4(l1, r1, 4)  L4(l2, r2, 8)  L4(l3, r3, 12)
        L4(l0, r4, 16) L4(l1, r5, 20) L4(l2, r6, 24) L4(l3, r7, 28)
        const float logit = (l0 + l1) + (l2 + l3);

        const float m = wave_max(logit);
        const float p = __expf(logit - m);
        const float S = wave_sum(p);
        const float prob = p * __builtin_amdgcn_rcpf(S);

        S4(r0, 0)  S4(r1, 4)  S4(r2, 8)  S4(r3, 12)
        S4(r4, 16) S4(r5, 20) S4(r6, 24) S4(r7, 28)
    }
#undef L4
#undef S4

    // flush: per-wave rows into padded buf, block-reduce, write part[b,c]
    {
        float4* dst = (float4*)&buf[(wave * OUT_CAPS + lane) * TSTR];
#pragma unroll
        for (int q = 0; q < 8; ++q)
            dst[q] = make_float4(s[4 * q], s[4 * q + 1], s[4 * q + 2], s[4 * q + 3]);
    }
    __syncthreads();
    {
        float4* pb4 = (float4*)(part_out + ((size_t)b * NCHUNK + c) * OUT_CAPS * IN_LEN);
        for (int e = tid; e < OUT_CAPS * IN_LEN / 4; e += 256) {
            const int o = e >> 3, q4 = (e & 7) * 4;
            const float4 a0 = *(const float4*)&buf[(0 * OUT_CAPS + o) * TSTR + q4];
            const float4 a1 = *(const float4*)&buf[(1 * OUT_CAPS + o) * TSTR + q4];
            const float4 a2 = *(const float4*)&buf[(2 * OUT_CAPS + o) * TSTR + q4];
            const float4 a3 = *(const float4*)&buf[(3 * OUT_CAPS + o) * TSTR + q4];
            pb4[e] = make_float4(a0.x + a1.x + a2.x + a3.x,
                                 a0.y + a1.y + a2.y + a3.y,
                                 a0.z + a1.z + a2.z + a3.z,
                                 a0.w + a1.w + a2.w + a3.w);
        }
    }
}

// ---------------------------------------------------------------------------
// k_init: s0 = (1/64) sum_n x[b,n,:]; u = W@s0; squash; T = W^T@v0.
// 32 blocks — the single cold-HBM read of x; warms L3 for the pass kernels.
// (byte-identical to the R0/R4-proven version)
// ---------------------------------------------------------------------------
__global__ __launch_bounds__(256) void k_init(const float* __restrict__ x,
                                              const float* __restrict__ W,
                                              float* __restrict__ T) {
    const int b   = blockIdx.x;
    const int tid = threadIdx.x;
    const float* xb = x + (size_t)b * IN_CAPS * IN_LEN;

    __shared__ float4 red4[32][8];
    {
        const int q = tid & 7;
        const int g = tid >> 3;
        float4 acc = make_float4(0.f, 0.f, 0.f, 0.f);
        for (int n = g; n < IN_CAPS; n += 32) {
            const float4 v = *(const float4*)(xb + n * IN_LEN + q * 4);
            acc.x += v.x; acc.y += v.y; acc.z += v.z; acc.w += v.w;
        }
        red4[g][q] = acc;
    }
    __syncthreads();
    __shared__ float s0[IN_LEN];
    if (tid < 8) {
        float4 v = make_float4(0.f, 0.f, 0.f, 0.f);
        for (int g = 0; g < 32; ++g) {
            const float4 r = red4[g][tid];
            v.x += r.x; v.y += r.y; v.z += r.z; v.w += r.w;
        }
        const float inv = 1.f / 64.f;   // uniform softmax prob at r=0
        s0[tid * 4 + 0] = v.x * inv;
        s0[tid * 4 + 1] = v.y * inv;
        s0[tid * 4 + 2] = v.z * inv;
        s0[tid * 4 + 3] = v.w * inv;
    }
    __syncthreads();

    __shared__ float u[OUT_CAPS * OUT_LEN];
    for (int e = tid; e < OUT_CAPS * OUT_LEN; e += 256) {
        const float* wrow = W + (size_t)e * IN_LEN;
        float a = 0.f;
#pragma unroll
        for (int i = 0; i < IN_LEN; ++i) a = fmaf(wrow[i], s0[i], a);
        u[e] = a;
    }
    __syncthreads();

    __shared__ float scale[OUT_CAPS];
    if (tid < OUT_CAPS) {
        float ns = 0.f;
#pragma unroll
        for (int l = 0; l < OUT_LEN; ++l) { const float v = u[tid * OUT_LEN + l]; ns = fmaf(v, v, ns); }
        scale[tid] = sqrtf(ns) / (1.f + ns);
    }
    __syncthreads();

    for (int e = tid; e < OUT_CAPS * IN_LEN; e += 256) {
        const int o = e >> 5, i = e & 31;
        float a = 0.f;
#pragma unroll
        for (int l = 0; l < OUT_LEN; ++l)
            a = fmaf(W[((size_t)o * OUT_LEN + l) * IN_LEN + i], u[o * OUT_LEN + l], a);
        T[(size_t)b * OUT_CAPS * IN_LEN + e] = a * scale[o];
    }
}

// ---------------------------------------------------------------------------
// k_pass1: routing iter 1 (R4-proven body), t[] from global T, XCD swizzle.
// ---------------------------------------------------------------------------
__global__ __launch_bounds__(256, 2) void k_pass1(const float* __restrict__ x,
                                                  const float* __restrict__ T,
                                                  float* __restrict__ part) {
    DECODE_BC(blockIdx.x, b, c)
    const int tid  = threadIdx.x;
    const int lane = tid & 63;
    const int wave = __builtin_amdgcn_readfirstlane(tid >> 6);

    __shared__ __align__(16) float buf[PASS_WAVES * OUT_CAPS * TSTR];    // 36 KB

    pass_and_flush(x, T + (size_t)b * OUT_CAPS * IN_LEN, IN_LEN,
                   buf, part, b, c, tid, lane, wave);
}

// ---------------------------------------------------------------------------
// kB: redundant vt-reduce (part -> s -> u -> squash; T1 = T0 + W^T v1 in LDS),
//     then routing iter 2 writing part2 (race-free vs part).
// ---------------------------------------------------------------------------
__global__ __launch_bounds__(256, 2) void kB(const float* __restrict__ x,
                                             const float* __restrict__ W,
                                             const float* __restrict__ T,
                                             const float* __restrict__ part,
                                             float* __restrict__ part2) {
    DECODE_BC(blockIdx.x, b, c)
    const int tid  = threadIdx.x;
    const int lane = tid & 63;
    const int wave = __builtin_amdgcn_readfirstlane(tid >> 6);

    __shared__ __align__(16) float T_lds[OUT_CAPS * TSTR];               // 9 KB
    __shared__ __align__(16) float buf[PASS_WAVES * OUT_CAPS * TSTR];    // 36 KB

    float* s_lds = buf;          // 2048 floats
    float* uu    = buf + 2048;   // 2048
    float* sc    = buf + 4096;   // 64

    // ---- redundant vt-reduce (R6-proven) ----
    {
        const float4* pb4 = (const float4*)(part + (size_t)b * NCHUNK * OUT_CAPS * IN_LEN);
        for (int e = tid; e < OUT_CAPS * IN_LEN / 4; e += 256) {
            float4 acc = make_float4(0.f, 0.f, 0.f, 0.f);
#pragma unroll
            for (int cc = 0; cc < NCHUNK; ++cc) {
                const float4 v = pb4[cc * (OUT_CAPS * IN_LEN / 4) + e];
                acc.x += v.x; acc.y += v.y; acc.z += v.z; acc.w += v.w;
            }
            ((float4*)s_lds)[e] = acc;
        }
    }
    __syncthreads();
    for (int e = tid; e < OUT_CAPS * OUT_LEN; e += 256) {
        const int o = e >> 5;
        const float* wrow = W + (size_t)e * IN_LEN;
        const float* srow = s_lds + o * IN_LEN;
        float a = 0.f;
#pragma unroll
        for (int i = 0; i < IN_LEN; ++i) a = fmaf(wrow[i], srow[i], a);
        uu[e] = a;
    }
    __syncthreads();
    if (tid < OUT_CAPS) {
        float ns = 0.f;
#pragma unroll
        for (int l = 0; l < OUT_LEN; ++l) { const float v = uu[tid * OUT_LEN + l]; ns = fmaf(v, v, ns); }
        sc[tid] = sqrtf(ns) / (1.f + ns);
    }
    __syncthreads();

    // T1 = T0 + W^T @ (uu * sc)  -> LDS
    for (int e = tid; e < OUT_CAPS * IN_LEN; e += 256) {
        const int o = e >> 5, i = e & 31;
        float a = 0.f;
#pragma unroll
        for (int l = 0; l < OUT_LEN; ++l)
            a = fmaf(W[((size_t)o * OUT_LEN + l) * IN_LEN + i], uu[o * OUT_LEN + l], a);
        T_lds[o * TSTR + i] = T[(size_t)b * OUT_CAPS * IN_LEN + e] + a * sc[o];
    }
    __syncthreads();

    pass_and_flush(x, T_lds, TSTR, buf, part2, b, c, tid, lane, wave);
}

// ---------------------------------------------------------------------------
// kC: final vt, split by o-group. 256 blocks = 32 b x 8 groups of 8 o.
// (R6-proven; reads part2)
// ---------------------------------------------------------------------------
__global__ __launch_bounds__(256) void kC(const float* __restrict__ W,
                                          const float* __restrict__ part2,
                                          float* __restrict__ out) {
    const int b   = blockIdx.x >> 3;
    const int og  = blockIdx.x & 7;
    const int tid = threadIdx.x;
    const int ol  = tid >> 5;            // 0..7 local o
    const int i   = tid & 31;            // input index / later l
    const int o   = og * 8 + ol;

    float a = 0.f;
    const float* pb = part2 + (size_t)b * NCHUNK * OUT_CAPS * IN_LEN + o * IN_LEN + i;
#pragma unroll
    for (int cc = 0; cc < NCHUNK; ++cc) a += pb[cc * OUT_CAPS * IN_LEN];

    __shared__ float s_lds[8][33];
    s_lds[ol][i] = a;
    __syncthreads();

    const float* wrow = W + ((size_t)o * OUT_LEN + i) * IN_LEN;
    float u = 0.f;
#pragma unroll
    for (int k = 0; k < IN_LEN; ++k) u = fmaf(wrow[k], s_lds[ol][k], u);

    float ns = u * u;
    ns += __shfl_xor(ns, 1, 64);
    ns += __shfl_xor(ns, 2, 64);
    ns += __shfl_xor(ns, 4, 64);
    ns += __shfl_xor(ns, 8, 64);
    ns += __shfl_xor(ns, 16, 64);
    const float scale = sqrtf(ns) / (1.f + ns);

    out[((size_t)b * OUT_CAPS + o) * OUT_LEN + i] = u * scale;
}

extern "C" void kernel_launch(void* const* d_in, const int* in_sizes, int n_in,
                              void* d_out, int out_size, void* d_ws, size_t ws_size,
                              hipStream_t stream) {
    const float* x = (const float*)d_in[0];   // [32,1152,32]
    const float* W = (const float*)d_in[1];   // [64,32,32]
    float* out = (float*)d_out;               // [32,64,32]

    float* T     = (float*)d_ws;                          // 256 KB
    float* part  = T + (size_t)N_B * OUT_CAPS * IN_LEN;   // 4 MB (iter-1 partials)
    float* part2 = part + (size_t)N_B * NCHUNK * OUT_CAPS * IN_LEN; // 4 MB (iter-2)

    k_init <<<N_B,          256, 0, stream>>>(x, W, T);
    k_pass1<<<N_B * NCHUNK, 256, 0, stream>>>(x, T, part);          // routing iter 1
    kB     <<<N_B * NCHUNK, 256, 0, stream>>>(x, W, T, part, part2); // vt1 + iter 2
    kC     <<<N_B * 8,      256, 0, stream>>>(W, part2, out);        // final vt
}